// Round 1
// baseline (521.281 us; speedup 1.0000x reference)
//
#include <hip/hip_runtime.h>
#include <hip/hip_bf16.h>
#include <math.h>

// ---------------------------------------------------------------------------
// GAT 2-layer pipeline, CSR-by-dst + one-wave-per-node online-softmax agg.
// N=50000, E=800000 (+N self-loops), Fin=128, H=8, C=16, HC=128, Fout=40.
// ---------------------------------------------------------------------------

#define LRELU(v) ((v) > 0.f ? (v) : 0.2f * (v))

// ---- GEMM1: h1 = x @ W1 (f32, [N,128]x[128,128]), fused a_s1/a_d1 ----------
__global__ __launch_bounds__(128) void gemm1_k(
    const float* __restrict__ x, const float* __restrict__ W,
    const float* __restrict__ atts, const float* __restrict__ attd,
    float* __restrict__ h1, float* __restrict__ as1, float* __restrict__ ad1,
    int N)
{
  __shared__ float Ws[64 * 128];   // 32 KB: K-half x all 128 cols
  __shared__ float xs[32 * 64];    // 8 KB: 32 rows x K-half
  const int t = threadIdx.x;
  const int row0 = blockIdx.x * 32;

  float acc[4][8];
#pragma unroll
  for (int a = 0; a < 4; ++a)
#pragma unroll
    for (int r = 0; r < 8; ++r) acc[a][r] = 0.f;

  for (int kb = 0; kb < 2; ++kb) {
    __syncthreads();
    for (int i = t; i < 64 * 128; i += 128) Ws[i] = W[kb * 64 * 128 + i];
    for (int i = t; i < 32 * 64; i += 128) {
      int r = i >> 6, k = i & 63;
      int rr = row0 + r;
      xs[i] = (rr < N) ? x[(size_t)rr * 128 + kb * 64 + k] : 0.f;
    }
    __syncthreads();
    const float4* xs4 = reinterpret_cast<const float4*>(xs);
    for (int k4 = 0; k4 < 16; ++k4) {
      float w0 = Ws[(k4 * 4 + 0) * 128 + t];
      float w1 = Ws[(k4 * 4 + 1) * 128 + t];
      float w2 = Ws[(k4 * 4 + 2) * 128 + t];
      float w3 = Ws[(k4 * 4 + 3) * 128 + t];
#pragma unroll
      for (int rg = 0; rg < 4; ++rg) {
#pragma unroll
        for (int r = 0; r < 8; ++r) {
          float4 xv = xs4[(rg * 8 + r) * 16 + k4];
          float a = acc[rg][r];
          a += xv.x * w0; a += xv.y * w1; a += xv.z * w2; a += xv.w * w3;
          acc[rg][r] = a;
        }
      }
    }
  }

  const float asv = atts[t];   // att_src1 flat [h*16+c] == t
  const float adv = attd[t];
#pragma unroll
  for (int rg = 0; rg < 4; ++rg) {
#pragma unroll
    for (int r = 0; r < 8; ++r) {
      int rr = row0 + rg * 8 + r;
      if (rr >= N) continue;
      float v = acc[rg][r];
      h1[(size_t)rr * 128 + t] = v;
      float s = v * asv, d = v * adv;
#pragma unroll
      for (int off = 1; off < 16; off <<= 1) {
        s += __shfl_xor(s, off);
        d += __shfl_xor(d, off);
      }
      if ((t & 15) == 0) {
        int h = t >> 4;
        as1[rr * 8 + h] = s;
        ad1[rr * 8 + h] = d;
      }
    }
  }
}

// ---- CSR build ------------------------------------------------------------
__global__ void count_k(const int* __restrict__ ei, int E, int N,
                        int* __restrict__ cnt)
{
  int e = blockIdx.x * blockDim.x + threadIdx.x;
  if (e >= E + N) return;
  int d = (e < E) ? ei[E + e] : (e - E);
  atomicAdd(&cnt[d], 1);
}

__global__ __launch_bounds__(1024) void scan_k(const int* __restrict__ cnt,
                                               int* __restrict__ rowptr, int N)
{
  __shared__ int wsum[16];
  __shared__ int base;
  const int t = threadIdx.x, lane = t & 63, wid = t >> 6;
  if (t == 0) { base = 0; rowptr[0] = 0; }
  __syncthreads();
  for (int start = 0; start < N; start += 1024) {
    int i = start + t;
    int x = (i < N) ? cnt[i] : 0;
#pragma unroll
    for (int off = 1; off < 64; off <<= 1) {
      int y = __shfl_up(x, off);
      if (lane >= off) x += y;
    }
    if (lane == 63) wsum[wid] = x;
    __syncthreads();
    if (wid == 0) {
      int w = (lane < 16) ? wsum[lane] : 0;
#pragma unroll
      for (int off = 1; off < 16; off <<= 1) {
        int y = __shfl_up(w, off);
        if (lane >= off) w += y;
      }
      if (lane < 16) wsum[lane] = w;
    }
    __syncthreads();
    int incl = x + (wid > 0 ? wsum[wid - 1] : 0) + base;
    if (i < N) rowptr[i + 1] = incl;
    __syncthreads();
    if (t == 0) base += wsum[15];
    __syncthreads();
  }
}

__global__ void scatter_k(const int* __restrict__ ei, int E, int N,
                          const int* __restrict__ rowptr, int* __restrict__ cnt,
                          int* __restrict__ col)
{
  int e = blockIdx.x * blockDim.x + threadIdx.x;
  if (e >= E + N) return;
  int s = (e < E) ? ei[e] : (e - E);
  int d = (e < E) ? ei[E + e] : (e - E);
  int pos = atomicAdd(&cnt[d], 1);
  col[rowptr[d] + pos] = s;
}

// ---- AGG1: per-node online softmax + aggregate + bias + BN + ELU ----------
__global__ __launch_bounds__(256) void agg1_k(
    const float* __restrict__ h1, const float* __restrict__ as1,
    const float* __restrict__ ad1, const int* __restrict__ rowptr,
    const int* __restrict__ col, const float* __restrict__ b1,
    const float* __restrict__ gamma, const float* __restrict__ beta,
    const float* __restrict__ mean, const float* __restrict__ var,
    float* __restrict__ hmid, int N)
{
  const int wid = threadIdx.x >> 6, lane = threadIdx.x & 63;
  const int n = blockIdx.x * 4 + wid;
  if (n >= N) return;
  const int h0 = lane >> 4;            // head for channel c0
  const int c0 = lane, c1 = lane + 64; // two channels per lane
  const float adA = ad1[n * 8 + h0];
  const float adB = ad1[n * 8 + h0 + 4];

  float m0 = -INFINITY, m1 = -INFINITY;
  float d0 = 0.f, d1 = 0.f, a0 = 0.f, a1 = 0.f;
  const int jb = rowptr[n], je = rowptr[n + 1];
  for (int j = jb; j < je; ++j) {
    int s = col[j];
    float e0 = LRELU(as1[s * 8 + h0] + adA);
    float e1 = LRELU(as1[s * 8 + h0 + 4] + adB);
    float v0 = h1[(size_t)s * 128 + c0];
    float v1 = h1[(size_t)s * 128 + c1];
    float nm0 = fmaxf(m0, e0);
    float nm1 = fmaxf(m1, e1);
    float sc0 = __expf(m0 - nm0);      // first iter: exp(-inf)=0
    float sc1 = __expf(m1 - nm1);
    float p0 = __expf(e0 - nm0);
    float p1 = __expf(e1 - nm1);
    d0 = d0 * sc0 + p0;
    d1 = d1 * sc1 + p1;
    a0 = a0 * sc0 + p0 * v0;
    a1 = a1 * sc1 + p1 * v1;
    m0 = nm0; m1 = nm1;
  }
  float o0 = a0 / (d0 + 1e-16f) + b1[c0];
  float o1 = a1 / (d1 + 1e-16f) + b1[c1];
  float bn0 = (o0 - mean[c0]) * rsqrtf(var[c0] + 1e-5f) * gamma[c0] + beta[c0];
  float bn1 = (o1 - mean[c1]) * rsqrtf(var[c1] + 1e-5f) * gamma[c1] + beta[c1];
  hmid[(size_t)n * 128 + c0] = bn0 > 0.f ? bn0 : expm1f(bn0);
  hmid[(size_t)n * 128 + c1] = bn1 > 0.f ? bn1 : expm1f(bn1);
}

// ---- GEMM2: h2p = hmid @ W2 ([N,128]x[128,40]), fused a_s2/a_d2 -----------
__global__ __launch_bounds__(256) void gemm2_k(
    const float* __restrict__ hmid, const float* __restrict__ W2,
    const float* __restrict__ atts, const float* __restrict__ attd,
    float* __restrict__ h2p, float* __restrict__ as2, float* __restrict__ ad2,
    int N)
{
  __shared__ float Ws[128 * 40 + 64];
  const int t = threadIdx.x;
  for (int i = t; i < 128 * 40 + 64; i += 256)
    Ws[i] = (i < 128 * 40) ? W2[i] : 0.f;
  __syncthreads();
  const int lane = t & 63, wid = t >> 6;
  const bool act = lane < 40;
  const float asv = act ? atts[lane] : 0.f;
  const float adv = act ? attd[lane] : 0.f;
  const int stride = gridDim.x * 4;
  for (int n = blockIdx.x * 4 + wid; n < N; n += stride) {
    float xa = hmid[(size_t)n * 128 + lane];
    float xb = hmid[(size_t)n * 128 + 64 + lane];
    float acc = 0.f;
#pragma unroll 16
    for (int k = 0; k < 64; ++k) {
      float xv = __shfl(xa, k);
      acc += xv * Ws[k * 40 + lane];
    }
#pragma unroll 16
    for (int k = 0; k < 64; ++k) {
      float xv = __shfl(xb, k);
      acc += xv * Ws[(64 + k) * 40 + lane];
    }
    if (act) h2p[(size_t)n * 40 + lane] = acc;
    float s = acc * asv, d = acc * adv;
#pragma unroll
    for (int off = 1; off < 64; off <<= 1) {
      s += __shfl_xor(s, off);
      d += __shfl_xor(d, off);
    }
    if (lane == 0) { as2[n] = s; ad2[n] = d; }
  }
}

// ---- AGG2: per-node online softmax + aggregate + bias + log_softmax -------
__global__ __launch_bounds__(256) void agg2_k(
    const float* __restrict__ h2p, const float* __restrict__ as2,
    const float* __restrict__ ad2, const int* __restrict__ rowptr,
    const int* __restrict__ col, const float* __restrict__ b2,
    float* __restrict__ out, int N)
{
  const int wid = threadIdx.x >> 6, lane = threadIdx.x & 63;
  const int n = blockIdx.x * 4 + wid;
  if (n >= N) return;
  const bool act = lane < 40;
  const float adv = ad2[n];
  float m = -INFINITY, den = 0.f, acc = 0.f;
  const int jb = rowptr[n], je = rowptr[n + 1];
  for (int j = jb; j < je; ++j) {
    int s = col[j];
    float e = LRELU(as2[s] + adv);
    float v = act ? h2p[(size_t)s * 40 + lane] : 0.f;
    float nm = fmaxf(m, e);
    float sc = __expf(m - nm);
    float p = __expf(e - nm);
    den = den * sc + p;
    acc = acc * sc + p * v;
    m = nm;
  }
  float o = acc / (den + 1e-16f) + (act ? b2[lane] : 0.f);
  // row log_softmax over 40 lanes
  float mv = act ? o : -INFINITY;
#pragma unroll
  for (int off = 1; off < 64; off <<= 1) mv = fmaxf(mv, __shfl_xor(mv, off));
  float ex = act ? __expf(o - mv) : 0.f;
#pragma unroll
  for (int off = 1; off < 64; off <<= 1) ex += __shfl_xor(ex, off);
  float ls = logf(ex);
  if (act) out[(size_t)n * 40 + lane] = o - mv - ls;
}

// ---------------------------------------------------------------------------
extern "C" void kernel_launch(void* const* d_in, const int* in_sizes, int n_in,
                              void* d_out, int out_size, void* d_ws,
                              size_t ws_size, hipStream_t stream)
{
  const float* x      = (const float*)d_in[0];
  const int*   ei     = (const int*)d_in[1];
  const float* W1     = (const float*)d_in[2];
  const float* att_s1 = (const float*)d_in[3];
  const float* att_d1 = (const float*)d_in[4];
  const float* b1     = (const float*)d_in[5];
  const float* gamma  = (const float*)d_in[6];
  const float* beta   = (const float*)d_in[7];
  const float* mean   = (const float*)d_in[8];
  const float* var    = (const float*)d_in[9];
  const float* W2     = (const float*)d_in[10];
  const float* att_s2 = (const float*)d_in[11];
  const float* att_d2 = (const float*)d_in[12];
  const float* b2     = (const float*)d_in[13];
  float* out = (float*)d_out;

  const int N = in_sizes[0] / 128;
  const int E = in_sizes[1] / 2;
  const int Etot = E + N;

  char* ws = (char*)d_ws;
  size_t off = 0;
  auto alloc = [&](size_t bytes) -> void* {
    void* p = ws + off;
    off = (off + bytes + 255) & ~(size_t)255;
    return p;
  };
  float* h1   = (float*)alloc((size_t)N * 128 * 4);
  float* as1  = (float*)alloc((size_t)N * 8 * 4);
  float* ad1  = (float*)alloc((size_t)N * 8 * 4);
  float* hmid = (float*)alloc((size_t)N * 128 * 4);
  int* rowptr = (int*)alloc((size_t)(N + 1) * 4);
  int* cnt    = (int*)alloc((size_t)N * 4);
  int* col    = (int*)alloc((size_t)Etot * 4);
  // reuse dead layer-1 buffers for layer 2
  float* h2p = h1;
  float* as2 = as1;
  float* ad2 = ad1;

  hipMemsetAsync(cnt, 0, (size_t)N * 4, stream);

  gemm1_k<<<(N + 31) / 32, 128, 0, stream>>>(x, W1, att_s1, att_d1,
                                             h1, as1, ad1, N);
  count_k<<<(Etot + 255) / 256, 256, 0, stream>>>(ei, E, N, cnt);
  scan_k<<<1, 1024, 0, stream>>>(cnt, rowptr, N);
  hipMemsetAsync(cnt, 0, (size_t)N * 4, stream);
  scatter_k<<<(Etot + 255) / 256, 256, 0, stream>>>(ei, E, N, rowptr, cnt, col);

  agg1_k<<<(N + 3) / 4, 256, 0, stream>>>(h1, as1, ad1, rowptr, col, b1,
                                          gamma, beta, mean, var, hmid, N);
  gemm2_k<<<1024, 256, 0, stream>>>(hmid, W2, att_s2, att_d2,
                                    h2p, as2, ad2, N);
  agg2_k<<<(N + 3) / 4, 256, 0, stream>>>(h2p, as2, ad2, rowptr, col, b2,
                                          out, N);
}

// Round 2
// 338.172 us; speedup vs baseline: 1.5415x; 1.5415x over previous
//
#include <hip/hip_runtime.h>
#include <hip/hip_bf16.h>
#include <math.h>

#define LRELU(v) ((v) > 0.f ? (v) : 0.2f * (v))

__device__ inline unsigned int f2bf(float f) {
  unsigned int u = __float_as_uint(f);
  return (u + 0x7fffu + ((u >> 16) & 1u)) >> 16;   // RNE
}

// ---- GEMM1: h1 = x @ W1, fused a_s1/a_d1, h1 stored as packed bf16 --------
// grid ceil(N/64) x 256. Tile 64 rows x 128 cols, K in 4 chunks of 32.
// thread map: c4 = t&31 (col quad, cols 4*c4..), rg = t>>5 (rows rg*8..)
__global__ __launch_bounds__(256) void gemm1_k(
    const float* __restrict__ x, const float* __restrict__ W,
    const float* __restrict__ atts, const float* __restrict__ attd,
    unsigned int* __restrict__ h1b, float* __restrict__ as1,
    float* __restrict__ ad1, int N)
{
  __shared__ float xs[64 * 36];   // [row][k(32)+pad4]
  __shared__ float ws[32 * 128];  // [k][col]
  const int t = threadIdx.x;
  const int row0 = blockIdx.x * 64;
  const int c4 = t & 31;
  const int rg = t >> 5;

  float acc[8][4];
#pragma unroll
  for (int i = 0; i < 8; ++i)
#pragma unroll
    for (int j = 0; j < 4; ++j) acc[i][j] = 0.f;

  for (int kc = 0; kc < 4; ++kc) {
    __syncthreads();
#pragma unroll
    for (int i = 0; i < 2; ++i) {
      int idx = t + i * 256;           // 512 float4s of x
      int r = idx >> 3, kq = idx & 7;
      int rr = row0 + r;
      float4 v = make_float4(0.f, 0.f, 0.f, 0.f);
      if (rr < N)
        v = *reinterpret_cast<const float4*>(&x[(size_t)rr * 128 + kc * 32 + kq * 4]);
      *reinterpret_cast<float4*>(&xs[r * 36 + kq * 4]) = v;
    }
#pragma unroll
    for (int i = 0; i < 4; ++i) {
      int idx = t + i * 256;           // 1024 float4s of W
      int kk = idx >> 5, cq = idx & 31;
      *reinterpret_cast<float4*>(&ws[kk * 128 + cq * 4]) =
          *reinterpret_cast<const float4*>(&W[(size_t)(kc * 32 + kk) * 128 + cq * 4]);
    }
    __syncthreads();
#pragma unroll
    for (int k4 = 0; k4 < 8; ++k4) {
      float wk[4][4];
#pragma unroll
      for (int kk = 0; kk < 4; ++kk)
        *reinterpret_cast<float4*>(wk[kk]) =
            *reinterpret_cast<const float4*>(&ws[(k4 * 4 + kk) * 128 + c4 * 4]);
#pragma unroll
      for (int i = 0; i < 8; ++i) {
        float xr[4];
        *reinterpret_cast<float4*>(xr) =
            *reinterpret_cast<const float4*>(&xs[(rg * 8 + i) * 36 + k4 * 4]);
#pragma unroll
        for (int kk = 0; kk < 4; ++kk)
#pragma unroll
          for (int j = 0; j < 4; ++j)
            acc[i][j] += xr[kk] * wk[kk][j];
      }
    }
  }

  float asv[4], adv[4];
  *reinterpret_cast<float4*>(asv) = *reinterpret_cast<const float4*>(&atts[c4 * 4]);
  *reinterpret_cast<float4*>(adv) = *reinterpret_cast<const float4*>(&attd[c4 * 4]);
  const int head = c4 >> 2;
#pragma unroll
  for (int i = 0; i < 8; ++i) {
    int rr = row0 + rg * 8 + i;
    if (rr >= N) continue;
    unsigned int u0 = f2bf(acc[i][0]) | (f2bf(acc[i][1]) << 16);
    unsigned int u1 = f2bf(acc[i][2]) | (f2bf(acc[i][3]) << 16);
    *reinterpret_cast<uint2*>(&h1b[(size_t)rr * 64 + c4 * 2]) = make_uint2(u0, u1);
    float s = acc[i][0] * asv[0] + acc[i][1] * asv[1] +
              acc[i][2] * asv[2] + acc[i][3] * asv[3];
    float d = acc[i][0] * adv[0] + acc[i][1] * adv[1] +
              acc[i][2] * adv[2] + acc[i][3] * adv[3];
    s += __shfl_xor(s, 1); s += __shfl_xor(s, 2);
    d += __shfl_xor(d, 1); d += __shfl_xor(d, 2);
    if ((c4 & 3) == 0) { as1[rr * 8 + head] = s; ad1[rr * 8 + head] = d; }
  }
}

// ---- CSR build ------------------------------------------------------------
__global__ void count_k(const int* __restrict__ ei, int E, int N,
                        int* __restrict__ cnt)
{
  int e = blockIdx.x * blockDim.x + threadIdx.x;
  if (e >= E + N) return;
  int d = (e < E) ? ei[E + e] : (e - E);
  atomicAdd(&cnt[d], 1);
}

// phase A: per-block (1024 elems) inclusive scan into rowptr[+1], block sums
__global__ __launch_bounds__(256) void scanA_k(const int* __restrict__ cnt,
                                               int* __restrict__ rowptr,
                                               int* __restrict__ bsum, int N)
{
  __shared__ int wsum[4];
  const int t = threadIdx.x, lane = t & 63, wid = t >> 6;
  const int g4 = blockIdx.x * 256 + t;
  int4 v = make_int4(0, 0, 0, 0);
  if (g4 < (N >> 2)) v = reinterpret_cast<const int4*>(cnt)[g4];
  int s = v.x + v.y + v.z + v.w;
  int incl = s;
#pragma unroll
  for (int off = 1; off < 64; off <<= 1) {
    int y = __shfl_up(incl, off);
    if (lane >= off) incl += y;
  }
  if (lane == 63) wsum[wid] = incl;
  __syncthreads();
  if (t == 0) {
    int t0 = wsum[0], t1 = wsum[1], t2 = wsum[2], t3 = wsum[3];
    bsum[blockIdx.x] = t0 + t1 + t2 + t3;
    wsum[0] = 0; wsum[1] = t0; wsum[2] = t0 + t1; wsum[3] = t0 + t1 + t2;
  }
  __syncthreads();
  int ex = wsum[wid] + incl - s;
  int g = g4 * 4;
  if (g < N) {
    int p0 = ex + v.x, p1 = p0 + v.y, p2 = p1 + v.z, p3 = p2 + v.w;
    rowptr[g + 1] = p0; rowptr[g + 2] = p1;
    rowptr[g + 3] = p2; rowptr[g + 4] = p3;
  }
}

// phase B: exclusive scan of block sums (single wave)
__global__ void scanB_k(int* bsum, int nb)
{
  const int lane = threadIdx.x;
  int v = (lane < nb) ? bsum[lane] : 0;
  int incl = v;
#pragma unroll
  for (int off = 1; off < 64; off <<= 1) {
    int y = __shfl_up(incl, off);
    if (lane >= off) incl += y;
  }
  if (lane < nb) bsum[lane] = incl - v;
}

// phase C: add block offsets
__global__ __launch_bounds__(256) void scanC_k(int* __restrict__ rowptr,
                                               const int* __restrict__ bsum,
                                               int N)
{
  const int b = blockIdx.x;
  if (b == 0) {
    if (threadIdx.x == 0) rowptr[0] = 0;
    return;
  }
  int add = bsum[b];
  int g = (b * 256 + threadIdx.x) * 4;
  if (g < N) {
    rowptr[g + 1] += add; rowptr[g + 2] += add;
    rowptr[g + 3] += add; rowptr[g + 4] += add;
  }
}

__global__ void scatter_k(const int* __restrict__ ei, int E, int N,
                          const int* __restrict__ rowptr, int* __restrict__ cnt,
                          int* __restrict__ col)
{
  int e = blockIdx.x * blockDim.x + threadIdx.x;
  if (e >= E + N) return;
  int s = (e < E) ? ei[e] : (e - E);
  int d = (e < E) ? ei[E + e] : (e - E);
  int pos = atomicAdd(&cnt[d], 1);
  col[rowptr[d] + pos] = s;
}

// ---- AGG1: wave/node online softmax + aggregate + bias + BN + ELU ---------
// lane owns channels {2*lane, 2*lane+1} (same head h=lane>>3): 1 softmax state
__global__ __launch_bounds__(256) void agg1_k(
    const unsigned int* __restrict__ h1b, const float* __restrict__ as1,
    const float* __restrict__ ad1, const int* __restrict__ rowptr,
    const int* __restrict__ col, const float* __restrict__ b1,
    const float* __restrict__ gamma, const float* __restrict__ beta,
    const float* __restrict__ mean, const float* __restrict__ var,
    float* __restrict__ hmid, int N)
{
  const int wid = threadIdx.x >> 6, lane = threadIdx.x & 63;
  const int n = blockIdx.x * 4 + wid;
  if (n >= N) return;
  const int h = lane >> 3;
  const int c0 = lane * 2;
  const float adv = ad1[n * 8 + h];
  float m = -INFINITY, den = 0.f, a0 = 0.f, a1 = 0.f;
  const int jb = rowptr[n], je = rowptr[n + 1];
  for (int j = jb; j < je; ++j) {
    int s = col[j];
    float e = LRELU(as1[s * 8 + h] + adv);
    unsigned int u = h1b[(size_t)s * 64 + lane];
    float v0 = __uint_as_float(u << 16);
    float v1 = __uint_as_float(u & 0xffff0000u);
    float nm = fmaxf(m, e);
    float sc = __expf(m - nm);
    float p = __expf(e - nm);
    den = den * sc + p;
    a0 = a0 * sc + p * v0;
    a1 = a1 * sc + p * v1;
    m = nm;
  }
  float r = 1.f / (den + 1e-16f);
  float o0 = a0 * r + b1[c0];
  float o1 = a1 * r + b1[c0 + 1];
  float bn0 = (o0 - mean[c0]) * rsqrtf(var[c0] + 1e-5f) * gamma[c0] + beta[c0];
  float bn1 = (o1 - mean[c0 + 1]) * rsqrtf(var[c0 + 1] + 1e-5f) * gamma[c0 + 1] + beta[c0 + 1];
  float2 o;
  o.x = bn0 > 0.f ? bn0 : expm1f(bn0);
  o.y = bn1 > 0.f ? bn1 : expm1f(bn1);
  *reinterpret_cast<float2*>(&hmid[(size_t)n * 128 + c0]) = o;
}

// ---- GEMM2: h2p = hmid @ W2 (128->40), fused a_s2/a_d2 --------------------
// grid ceil(N/128) x 256. lane: ng=lane>>3 (4 nodes), cg=lane&7 (5 cols)
__global__ __launch_bounds__(256) void gemm2_k(
    const float* __restrict__ hmid, const float* __restrict__ W2,
    const float* __restrict__ atts, const float* __restrict__ attd,
    float* __restrict__ h2p, float* __restrict__ as2, float* __restrict__ ad2,
    int N)
{
  __shared__ float hm[128 * 36];
  __shared__ float w2t[40 * 36];
  const int t = threadIdx.x;
  const int n0 = blockIdx.x * 128;
  const int lane = t & 63, w = t >> 6;
  const int ng = lane >> 3, cg = lane & 7;
  const int nloc = w * 32 + ng * 4;

  float acc[4][5];
#pragma unroll
  for (int i = 0; i < 4; ++i)
#pragma unroll
    for (int j = 0; j < 5; ++j) acc[i][j] = 0.f;

  for (int kc = 0; kc < 4; ++kc) {
    __syncthreads();
#pragma unroll
    for (int i = 0; i < 4; ++i) {
      int idx = t + i * 256;           // 1024 float4s of hmid
      int r = idx >> 3, kq = idx & 7;
      int rr = n0 + r;
      float4 v = make_float4(0.f, 0.f, 0.f, 0.f);
      if (rr < N)
        v = *reinterpret_cast<const float4*>(&hmid[(size_t)rr * 128 + kc * 32 + kq * 4]);
      *reinterpret_cast<float4*>(&hm[r * 36 + kq * 4]) = v;
    }
#pragma unroll
    for (int i = 0; i < 5; ++i) {
      int flat = t + i * 256;          // 1280 scalars of W2 (transpose)
      int c = flat >> 5, kk = flat & 31;
      w2t[c * 36 + kk] = W2[(size_t)(kc * 32 + kk) * 40 + c];
    }
    __syncthreads();
#pragma unroll
    for (int k4 = 0; k4 < 8; ++k4) {
      float hv[4][4];
#pragma unroll
      for (int i = 0; i < 4; ++i)
        *reinterpret_cast<float4*>(hv[i]) =
            *reinterpret_cast<const float4*>(&hm[(nloc + i) * 36 + k4 * 4]);
      float wv[5][4];
#pragma unroll
      for (int j = 0; j < 5; ++j)
        *reinterpret_cast<float4*>(wv[j]) =
            *reinterpret_cast<const float4*>(&w2t[(cg * 5 + j) * 36 + k4 * 4]);
#pragma unroll
      for (int i = 0; i < 4; ++i)
#pragma unroll
        for (int j = 0; j < 5; ++j)
#pragma unroll
          for (int kk = 0; kk < 4; ++kk)
            acc[i][j] += hv[i][kk] * wv[j][kk];
    }
  }

  float asv[5], adv[5];
#pragma unroll
  for (int j = 0; j < 5; ++j) { asv[j] = atts[cg * 5 + j]; adv[j] = attd[cg * 5 + j]; }
#pragma unroll
  for (int i = 0; i < 4; ++i) {
    int n = n0 + nloc + i;
    if (n >= N) continue;
    float ps = 0.f, pd = 0.f;
#pragma unroll
    for (int j = 0; j < 5; ++j) { ps += acc[i][j] * asv[j]; pd += acc[i][j] * adv[j]; }
#pragma unroll
    for (int off = 1; off < 8; off <<= 1) {
      ps += __shfl_xor(ps, off);
      pd += __shfl_xor(pd, off);
    }
#pragma unroll
    for (int j = 0; j < 5; ++j) h2p[(size_t)n * 40 + cg * 5 + j] = acc[i][j];
    if (cg == 0) { as2[n] = ps; ad2[n] = pd; }
  }
}

// ---- AGG2: wave/node online softmax + aggregate + bias + log_softmax ------
__global__ __launch_bounds__(256) void agg2_k(
    const float* __restrict__ h2p, const float* __restrict__ as2,
    const float* __restrict__ ad2, const int* __restrict__ rowptr,
    const int* __restrict__ col, const float* __restrict__ b2,
    float* __restrict__ out, int N)
{
  const int wid = threadIdx.x >> 6, lane = threadIdx.x & 63;
  const int n = blockIdx.x * 4 + wid;
  if (n >= N) return;
  const bool act = lane < 40;
  const float adv = ad2[n];
  float m = -INFINITY, den = 0.f, acc = 0.f;
  const int jb = rowptr[n], je = rowptr[n + 1];
  for (int j = jb; j < je; ++j) {
    int s = col[j];
    float e = LRELU(as2[s] + adv);
    float v = act ? h2p[(size_t)s * 40 + lane] : 0.f;
    float nm = fmaxf(m, e);
    float sc = __expf(m - nm);
    float p = __expf(e - nm);
    den = den * sc + p;
    acc = acc * sc + p * v;
    m = nm;
  }
  float o = acc / (den + 1e-16f) + (act ? b2[lane] : 0.f);
  float mv = act ? o : -INFINITY;
#pragma unroll
  for (int off = 1; off < 64; off <<= 1) mv = fmaxf(mv, __shfl_xor(mv, off));
  float ex = act ? __expf(o - mv) : 0.f;
#pragma unroll
  for (int off = 1; off < 64; off <<= 1) ex += __shfl_xor(ex, off);
  float ls = logf(ex);
  if (act) out[(size_t)n * 40 + lane] = o - mv - ls;
}

// ---------------------------------------------------------------------------
extern "C" void kernel_launch(void* const* d_in, const int* in_sizes, int n_in,
                              void* d_out, int out_size, void* d_ws,
                              size_t ws_size, hipStream_t stream)
{
  const float* x      = (const float*)d_in[0];
  const int*   ei     = (const int*)d_in[1];
  const float* W1     = (const float*)d_in[2];
  const float* att_s1 = (const float*)d_in[3];
  const float* att_d1 = (const float*)d_in[4];
  const float* b1     = (const float*)d_in[5];
  const float* gamma  = (const float*)d_in[6];
  const float* beta   = (const float*)d_in[7];
  const float* mean   = (const float*)d_in[8];
  const float* var    = (const float*)d_in[9];
  const float* W2     = (const float*)d_in[10];
  const float* att_s2 = (const float*)d_in[11];
  const float* att_d2 = (const float*)d_in[12];
  const float* b2     = (const float*)d_in[13];
  float* out = (float*)d_out;

  const int N = in_sizes[0] / 128;
  const int E = in_sizes[1] / 2;
  const int Etot = E + N;
  const int NB = (N + 1023) / 1024;   // scan blocks (N/4 int4s, 256/block)

  char* ws = (char*)d_ws;
  size_t off = 0;
  auto alloc = [&](size_t bytes) -> void* {
    void* p = ws + off;
    off = (off + bytes + 255) & ~(size_t)255;
    return p;
  };
  unsigned int* h1b = (unsigned int*)alloc((size_t)N * 64 * 4);  // bf16 pairs
  float* as1  = (float*)alloc((size_t)N * 8 * 4);
  float* ad1  = (float*)alloc((size_t)N * 8 * 4);
  float* hmid = (float*)alloc((size_t)N * 128 * 4);
  int* rowptr = (int*)alloc((size_t)(N + 1) * 4);
  int* cnt    = (int*)alloc((size_t)N * 4);
  int* col    = (int*)alloc((size_t)Etot * 4);
  int* bsum   = (int*)alloc(256 * 4);
  // layer-2 reuses dead layer-1 buffers
  float* h2p = (float*)h1b;   // N*40 f32 (8MB) <= N*64*4 (12.8MB)
  float* as2 = as1;
  float* ad2 = ad1;

  hipMemsetAsync(cnt, 0, (size_t)N * 4, stream);

  gemm1_k<<<(N + 63) / 64, 256, 0, stream>>>(x, W1, att_s1, att_d1,
                                             h1b, as1, ad1, N);
  count_k<<<(Etot + 255) / 256, 256, 0, stream>>>(ei, E, N, cnt);
  scanA_k<<<NB, 256, 0, stream>>>(cnt, rowptr, bsum, N);
  scanB_k<<<1, 64, 0, stream>>>(bsum, NB);
  scanC_k<<<NB, 256, 0, stream>>>(rowptr, bsum, N);
  hipMemsetAsync(cnt, 0, (size_t)N * 4, stream);
  scatter_k<<<(Etot + 255) / 256, 256, 0, stream>>>(ei, E, N, rowptr, cnt, col);

  agg1_k<<<(N + 3) / 4, 256, 0, stream>>>(h1b, as1, ad1, rowptr, col, b1,
                                          gamma, beta, mean, var, hmid, N);
  gemm2_k<<<(N + 127) / 128, 256, 0, stream>>>(hmid, W2, att_s2, att_d2,
                                               h2p, as2, ad2, N);
  agg2_k<<<(N + 3) / 4, 256, 0, stream>>>(h2p, as2, ad2, rowptr, col, b2,
                                          out, N);
}

// Round 5
// 243.270 us; speedup vs baseline: 2.1428x; 1.3901x over previous
//
#include <hip/hip_runtime.h>
#include <hip/hip_bf16.h>
#include <math.h>

#define LRELU(v) ((v) > 0.f ? (v) : 0.2f * (v))

__device__ inline unsigned int f2bf(float f) {
  unsigned int u = __float_as_uint(f);
  return (u + 0x7fffu + ((u >> 16) & 1u)) >> 16;   // RNE
}

// ---- GEMM1: h1 = x @ W1, fused a_s1/a_d1, h1 stored as packed bf16 --------
__global__ __launch_bounds__(256) void gemm1_k(
    const float* __restrict__ x, const float* __restrict__ W,
    const float* __restrict__ atts, const float* __restrict__ attd,
    unsigned int* __restrict__ h1b, float* __restrict__ as1,
    float* __restrict__ ad1, int N)
{
  __shared__ float xs[64 * 36];   // [row][k(32)+pad4]
  __shared__ float ws[32 * 128];  // [k][col]
  const int t = threadIdx.x;
  const int row0 = blockIdx.x * 64;
  const int c4 = t & 31;
  const int rg = t >> 5;

  float acc[8][4];
#pragma unroll
  for (int i = 0; i < 8; ++i)
#pragma unroll
    for (int j = 0; j < 4; ++j) acc[i][j] = 0.f;

  for (int kc = 0; kc < 4; ++kc) {
    __syncthreads();
#pragma unroll
    for (int i = 0; i < 2; ++i) {
      int idx = t + i * 256;           // 512 float4s of x
      int r = idx >> 3, kq = idx & 7;
      int rr = row0 + r;
      float4 v = make_float4(0.f, 0.f, 0.f, 0.f);
      if (rr < N)
        v = *reinterpret_cast<const float4*>(&x[(size_t)rr * 128 + kc * 32 + kq * 4]);
      *reinterpret_cast<float4*>(&xs[r * 36 + kq * 4]) = v;
    }
#pragma unroll
    for (int i = 0; i < 4; ++i) {
      int idx = t + i * 256;           // 1024 float4s of W
      int kk = idx >> 5, cq = idx & 31;
      *reinterpret_cast<float4*>(&ws[kk * 128 + cq * 4]) =
          *reinterpret_cast<const float4*>(&W[(size_t)(kc * 32 + kk) * 128 + cq * 4]);
    }
    __syncthreads();
#pragma unroll
    for (int k4 = 0; k4 < 8; ++k4) {
      float wk[4][4];
#pragma unroll
      for (int kk = 0; kk < 4; ++kk)
        *reinterpret_cast<float4*>(wk[kk]) =
            *reinterpret_cast<const float4*>(&ws[(k4 * 4 + kk) * 128 + c4 * 4]);
#pragma unroll
      for (int i = 0; i < 8; ++i) {
        float xr[4];
        *reinterpret_cast<float4*>(xr) =
            *reinterpret_cast<const float4*>(&xs[(rg * 8 + i) * 36 + k4 * 4]);
#pragma unroll
        for (int kk = 0; kk < 4; ++kk)
#pragma unroll
          for (int j = 0; j < 4; ++j)
            acc[i][j] += xr[kk] * wk[kk][j];
      }
    }
  }

  float asv[4], adv[4];
  *reinterpret_cast<float4*>(asv) = *reinterpret_cast<const float4*>(&atts[c4 * 4]);
  *reinterpret_cast<float4*>(adv) = *reinterpret_cast<const float4*>(&attd[c4 * 4]);
  const int head = c4 >> 2;
#pragma unroll
  for (int i = 0; i < 8; ++i) {
    int rr = row0 + rg * 8 + i;
    if (rr >= N) continue;
    unsigned int u0 = f2bf(acc[i][0]) | (f2bf(acc[i][1]) << 16);
    unsigned int u1 = f2bf(acc[i][2]) | (f2bf(acc[i][3]) << 16);
    *reinterpret_cast<uint2*>(&h1b[(size_t)rr * 64 + c4 * 2]) = make_uint2(u0, u1);
    float s = acc[i][0] * asv[0] + acc[i][1] * asv[1] +
              acc[i][2] * asv[2] + acc[i][3] * asv[3];
    float d = acc[i][0] * adv[0] + acc[i][1] * adv[1] +
              acc[i][2] * adv[2] + acc[i][3] * adv[3];
    s += __shfl_xor(s, 1); s += __shfl_xor(s, 2);
    d += __shfl_xor(d, 1); d += __shfl_xor(d, 2);
    if ((c4 & 3) == 0) { as1[rr * 8 + head] = s; ad1[rr * 8 + head] = d; }
  }
}

// ---- CSR build ------------------------------------------------------------
__global__ void count_k(const int* __restrict__ ei, int E, int N,
                        int* __restrict__ cnt)
{
  int e = blockIdx.x * blockDim.x + threadIdx.x;
  if (e >= E + N) return;
  int d = (e < E) ? ei[E + e] : (e - E);
  atomicAdd(&cnt[d], 1);
}

__global__ __launch_bounds__(256) void scanA_k(const int* __restrict__ cnt,
                                               int* __restrict__ rowptr,
                                               int* __restrict__ bsum, int N)
{
  __shared__ int wsum[4];
  const int t = threadIdx.x, lane = t & 63, wid = t >> 6;
  const int g4 = blockIdx.x * 256 + t;
  int4 v = make_int4(0, 0, 0, 0);
  if (g4 < (N >> 2)) v = reinterpret_cast<const int4*>(cnt)[g4];
  int s = v.x + v.y + v.z + v.w;
  int incl = s;
#pragma unroll
  for (int off = 1; off < 64; off <<= 1) {
    int y = __shfl_up(incl, off);
    if (lane >= off) incl += y;
  }
  if (lane == 63) wsum[wid] = incl;
  __syncthreads();
  if (t == 0) {
    int t0 = wsum[0], t1 = wsum[1], t2 = wsum[2], t3 = wsum[3];
    bsum[blockIdx.x] = t0 + t1 + t2 + t3;
    wsum[0] = 0; wsum[1] = t0; wsum[2] = t0 + t1; wsum[3] = t0 + t1 + t2;
  }
  __syncthreads();
  int ex = wsum[wid] + incl - s;
  int g = g4 * 4;
  if (g < N) {
    int p0 = ex + v.x, p1 = p0 + v.y, p2 = p1 + v.z, p3 = p2 + v.w;
    rowptr[g + 1] = p0; rowptr[g + 2] = p1;
    rowptr[g + 3] = p2; rowptr[g + 4] = p3;
  }
}

__global__ void scanB_k(int* bsum, int nb)
{
  const int lane = threadIdx.x;
  int v = (lane < nb) ? bsum[lane] : 0;
  int incl = v;
#pragma unroll
  for (int off = 1; off < 64; off <<= 1) {
    int y = __shfl_up(incl, off);
    if (lane >= off) incl += y;
  }
  if (lane < nb) bsum[lane] = incl - v;
}

__global__ __launch_bounds__(256) void scanC_k(int* __restrict__ rowptr,
                                               const int* __restrict__ bsum,
                                               int N)
{
  const int b = blockIdx.x;
  if (b == 0) {
    if (threadIdx.x == 0) rowptr[0] = 0;
    return;
  }
  int add = bsum[b];
  int g = (b * 256 + threadIdx.x) * 4;
  if (g < N) {
    rowptr[g + 1] += add; rowptr[g + 2] += add;
    rowptr[g + 3] += add; rowptr[g + 4] += add;
  }
}

__global__ void scatter_k(const int* __restrict__ ei, int E, int N,
                          const int* __restrict__ rowptr, int* __restrict__ cnt,
                          int* __restrict__ col)
{
  int e = blockIdx.x * blockDim.x + threadIdx.x;
  if (e >= E + N) return;
  int s = (e < E) ? ei[e] : (e - E);
  int d = (e < E) ? ei[E + e] : (e - E);
  int pos = atomicAdd(&cnt[d], 1);
  col[rowptr[d] + pos] = s;
}

// ---- AGG1: wave/node, no-max softmax (shift-invariant), unroll-4 ----------
// lane owns channels {2*lane, 2*lane+1} (same head h=lane>>3)
__global__ __launch_bounds__(256) void agg1_k(
    const unsigned int* __restrict__ h1b, const float* __restrict__ as1,
    const float* __restrict__ ad1, const int* __restrict__ rowptr,
    const int* __restrict__ col, const float* __restrict__ b1,
    const float* __restrict__ gamma, const float* __restrict__ beta,
    const float* __restrict__ mean, const float* __restrict__ var,
    float* __restrict__ hmid, int N)
{
  const int wid = threadIdx.x >> 6, lane = threadIdx.x & 63;
  const int n = blockIdx.x * 4 + wid;
  if (n >= N) return;
  const int h = lane >> 3;
  const int c0 = lane * 2;
  const float adv = ad1[n * 8 + h];
  float den = 0.f, a0 = 0.f, a1 = 0.f;
  const int jb = rowptr[n], je = rowptr[n + 1];
  int j = jb;
  for (; j + 4 <= je; j += 4) {
    int s0 = col[j], s1 = col[j + 1], s2 = col[j + 2], s3 = col[j + 3];
    float e0 = as1[s0 * 8 + h];
    float e1 = as1[s1 * 8 + h];
    float e2 = as1[s2 * 8 + h];
    float e3 = as1[s3 * 8 + h];
    unsigned int u0 = h1b[(size_t)s0 * 64 + lane];
    unsigned int u1 = h1b[(size_t)s1 * 64 + lane];
    unsigned int u2 = h1b[(size_t)s2 * 64 + lane];
    unsigned int u3 = h1b[(size_t)s3 * 64 + lane];
    e0 = LRELU(e0 + adv); e1 = LRELU(e1 + adv);
    e2 = LRELU(e2 + adv); e3 = LRELU(e3 + adv);
    float p0 = __expf(e0), p1 = __expf(e1);
    float p2 = __expf(e2), p3 = __expf(e3);
    den += p0; den += p1; den += p2; den += p3;
    a0 += p0 * __uint_as_float(u0 << 16);
    a1 += p0 * __uint_as_float(u0 & 0xffff0000u);
    a0 += p1 * __uint_as_float(u1 << 16);
    a1 += p1 * __uint_as_float(u1 & 0xffff0000u);
    a0 += p2 * __uint_as_float(u2 << 16);
    a1 += p2 * __uint_as_float(u2 & 0xffff0000u);
    a0 += p3 * __uint_as_float(u3 << 16);
    a1 += p3 * __uint_as_float(u3 & 0xffff0000u);
  }
  for (; j < je; ++j) {
    int s = col[j];
    float e = LRELU(as1[s * 8 + h] + adv);
    unsigned int u = h1b[(size_t)s * 64 + lane];
    float p = __expf(e);
    den += p;
    a0 += p * __uint_as_float(u << 16);
    a1 += p * __uint_as_float(u & 0xffff0000u);
  }
  float r = 1.f / (den + 1e-16f);
  float o0 = a0 * r + b1[c0];
  float o1 = a1 * r + b1[c0 + 1];
  float bn0 = (o0 - mean[c0]) * rsqrtf(var[c0] + 1e-5f) * gamma[c0] + beta[c0];
  float bn1 = (o1 - mean[c0 + 1]) * rsqrtf(var[c0 + 1] + 1e-5f) * gamma[c0 + 1] + beta[c0 + 1];
  float2 o;
  o.x = bn0 > 0.f ? bn0 : expm1f(bn0);
  o.y = bn1 > 0.f ? bn1 : expm1f(bn1);
  *reinterpret_cast<float2*>(&hmid[(size_t)n * 128 + c0]) = o;
}

// ---- GEMM2: h2p = hmid @ W2 (128->40), fused a_s2/a_d2 --------------------
__global__ __launch_bounds__(256) void gemm2_k(
    const float* __restrict__ hmid, const float* __restrict__ W2,
    const float* __restrict__ atts, const float* __restrict__ attd,
    float* __restrict__ h2p, float* __restrict__ as2, float* __restrict__ ad2,
    int N)
{
  __shared__ float hm[128 * 36];
  __shared__ float w2t[40 * 36];
  const int t = threadIdx.x;
  const int n0 = blockIdx.x * 128;
  const int lane = t & 63, w = t >> 6;
  const int ng = lane >> 3, cg = lane & 7;
  const int nloc = w * 32 + ng * 4;

  float acc[4][5];
#pragma unroll
  for (int i = 0; i < 4; ++i)
#pragma unroll
    for (int j = 0; j < 5; ++j) acc[i][j] = 0.f;

  for (int kc = 0; kc < 4; ++kc) {
    __syncthreads();
#pragma unroll
    for (int i = 0; i < 4; ++i) {
      int idx = t + i * 256;
      int r = idx >> 3, kq = idx & 7;
      int rr = n0 + r;
      float4 v = make_float4(0.f, 0.f, 0.f, 0.f);
      if (rr < N)
        v = *reinterpret_cast<const float4*>(&hmid[(size_t)rr * 128 + kc * 32 + kq * 4]);
      *reinterpret_cast<float4*>(&hm[r * 36 + kq * 4]) = v;
    }
#pragma unroll
    for (int i = 0; i < 5; ++i) {
      int flat = t + i * 256;
      int c = flat >> 5, kk = flat & 31;
      w2t[c * 36 + kk] = W2[(size_t)(kc * 32 + kk) * 40 + c];
    }
    __syncthreads();
#pragma unroll
    for (int k4 = 0; k4 < 8; ++k4) {
      float hv[4][4];
#pragma unroll
      for (int i = 0; i < 4; ++i)
        *reinterpret_cast<float4*>(hv[i]) =
            *reinterpret_cast<const float4*>(&hm[(nloc + i) * 36 + k4 * 4]);
      float wv[5][4];
#pragma unroll
      for (int j = 0; j < 5; ++j)
        *reinterpret_cast<float4*>(wv[j]) =
            *reinterpret_cast<const float4*>(&w2t[(cg * 5 + j) * 36 + k4 * 4]);
#pragma unroll
      for (int i = 0; i < 4; ++i)
#pragma unroll
        for (int j = 0; j < 5; ++j)
#pragma unroll
          for (int kk = 0; kk < 4; ++kk)
            acc[i][j] += hv[i][kk] * wv[j][kk];
    }
  }

  float asv[5], adv[5];
#pragma unroll
  for (int j = 0; j < 5; ++j) { asv[j] = atts[cg * 5 + j]; adv[j] = attd[cg * 5 + j]; }
#pragma unroll
  for (int i = 0; i < 4; ++i) {
    int n = n0 + nloc + i;
    if (n >= N) continue;
    float ps = 0.f, pd = 0.f;
#pragma unroll
    for (int j = 0; j < 5; ++j) { ps += acc[i][j] * asv[j]; pd += acc[i][j] * adv[j]; }
#pragma unroll
    for (int off = 1; off < 8; off <<= 1) {
      ps += __shfl_xor(ps, off);
      pd += __shfl_xor(pd, off);
    }
#pragma unroll
    for (int j = 0; j < 5; ++j) h2p[(size_t)n * 40 + cg * 5 + j] = acc[i][j];
    if (cg == 0) { as2[n] = ps; ad2[n] = pd; }
  }
}

// ---- AGG2: wave/node, no-max softmax, unroll-4, bias + log_softmax --------
__global__ __launch_bounds__(256) void agg2_k(
    const float* __restrict__ h2p, const float* __restrict__ as2,
    const float* __restrict__ ad2, const int* __restrict__ rowptr,
    const int* __restrict__ col, const float* __restrict__ b2,
    float* __restrict__ out, int N)
{
  const int wid = threadIdx.x >> 6, lane = threadIdx.x & 63;
  const int n = blockIdx.x * 4 + wid;
  if (n >= N) return;
  const bool act = lane < 40;
  const float adv = ad2[n];
  float den = 0.f, acc = 0.f;
  const int jb = rowptr[n], je = rowptr[n + 1];
  int j = jb;
  for (; j + 4 <= je; j += 4) {
    int s0 = col[j], s1 = col[j + 1], s2 = col[j + 2], s3 = col[j + 3];
    float e0 = as2[s0], e1 = as2[s1], e2 = as2[s2], e3 = as2[s3];
    float v0 = act ? h2p[(size_t)s0 * 40 + lane] : 0.f;
    float v1 = act ? h2p[(size_t)s1 * 40 + lane] : 0.f;
    float v2 = act ? h2p[(size_t)s2 * 40 + lane] : 0.f;
    float v3 = act ? h2p[(size_t)s3 * 40 + lane] : 0.f;
    e0 = LRELU(e0 + adv); e1 = LRELU(e1 + adv);
    e2 = LRELU(e2 + adv); e3 = LRELU(e3 + adv);
    float p0 = __expf(e0), p1 = __expf(e1);
    float p2 = __expf(e2), p3 = __expf(e3);
    den += p0; den += p1; den += p2; den += p3;
    acc += p0 * v0; acc += p1 * v1; acc += p2 * v2; acc += p3 * v3;
  }
  for (; j < je; ++j) {
    int s = col[j];
    float e = LRELU(as2[s] + adv);
    float v = act ? h2p[(size_t)s * 40 + lane] : 0.f;
    float p = __expf(e);
    den += p;
    acc += p * v;
  }
  float o = acc / (den + 1e-16f) + (act ? b2[lane] : 0.f);
  float mv = act ? o : -INFINITY;
#pragma unroll
  for (int off = 1; off < 64; off <<= 1) mv = fmaxf(mv, __shfl_xor(mv, off));
  float ex = act ? __expf(o - mv) : 0.f;
#pragma unroll
  for (int off = 1; off < 64; off <<= 1) ex += __shfl_xor(ex, off);
  float ls = logf(ex);
  if (act) out[(size_t)n * 40 + lane] = o - mv - ls;
}

// ---------------------------------------------------------------------------
extern "C" void kernel_launch(void* const* d_in, const int* in_sizes, int n_in,
                              void* d_out, int out_size, void* d_ws,
                              size_t ws_size, hipStream_t stream)
{
  const float* x      = (const float*)d_in[0];
  const int*   ei     = (const int*)d_in[1];
  const float* W1     = (const float*)d_in[2];
  const float* att_s1 = (const float*)d_in[3];
  const float* att_d1 = (const float*)d_in[4];
  const float* b1     = (const float*)d_in[5];
  const float* gamma  = (const float*)d_in[6];
  const float* beta   = (const float*)d_in[7];
  const float* mean   = (const float*)d_in[8];
  const float* var    = (const float*)d_in[9];
  const float* W2     = (const float*)d_in[10];
  const float* att_s2 = (const float*)d_in[11];
  const float* att_d2 = (const float*)d_in[12];
  const float* b2     = (const float*)d_in[13];
  float* out = (float*)d_out;

  const int N = in_sizes[0] / 128;
  const int E = in_sizes[1] / 2;
  const int Etot = E + N;
  const int NB = (N + 1023) / 1024;

  char* ws = (char*)d_ws;
  size_t off = 0;
  auto alloc = [&](size_t bytes) -> void* {
    void* p = ws + off;
    off = (off + bytes + 255) & ~(size_t)255;
    return p;
  };
  unsigned int* h1b = (unsigned int*)alloc((size_t)N * 64 * 4);
  float* as1  = (float*)alloc((size_t)N * 8 * 4);
  float* ad1  = (float*)alloc((size_t)N * 8 * 4);
  float* hmid = (float*)alloc((size_t)N * 128 * 4);
  int* rowptr = (int*)alloc((size_t)(N + 1) * 4);
  int* cnt    = (int*)alloc((size_t)N * 4);
  int* col    = (int*)alloc((size_t)Etot * 4);
  int* bsum   = (int*)alloc(256 * 4);
  float* h2p = (float*)h1b;
  float* as2 = as1;
  float* ad2 = ad1;

  hipMemsetAsync(cnt, 0, (size_t)N * 4, stream);

  gemm1_k<<<(N + 63) / 64, 256, 0, stream>>>(x, W1, att_s1, att_d1,
                                             h1b, as1, ad1, N);
  count_k<<<(Etot + 255) / 256, 256, 0, stream>>>(ei, E, N, cnt);
  scanA_k<<<NB, 256, 0, stream>>>(cnt, rowptr, bsum, N);
  scanB_k<<<1, 64, 0, stream>>>(bsum, NB);
  scanC_k<<<NB, 256, 0, stream>>>(rowptr, bsum, N);
  hipMemsetAsync(cnt, 0, (size_t)N * 4, stream);
  scatter_k<<<(Etot + 255) / 256, 256, 0, stream>>>(ei, E, N, rowptr, cnt, col);

  agg1_k<<<(N + 3) / 4, 256, 0, stream>>>(h1b, as1, ad1, rowptr, col, b1,
                                          gamma, beta, mean, var, hmid, N);
  gemm2_k<<<(N + 127) / 128, 256, 0, stream>>>(hmid, W2, att_s2, att_d2,
                                               h2p, as2, ad2, N);
  agg2_k<<<(N + 3) / 4, 256, 0, stream>>>(h2p, as2, ad2, rowptr, col, b2,
                                          out, N);
}